// Round 4
// baseline (1649.053 us; speedup 1.0000x reference)
//
#include <hip/hip_runtime.h>
#include <hip/hip_bf16.h>

// Problem constants (bert-base captioning decoder)
#define VCB 30522   // vocab
#define EMB 512     // embed size
#define ATTD 512    // attention dim
#define ENC 2048    // encoder dim
#define HD 512      // hidden dim
#define BB 32       // batch
#define NF 49       // image features
#define TSTEPS 20   // decode steps
#define EIN 2560    // EMB + ENC (lstm input)
#define KCAT 3072   // EIN + HD (fused gate GEMM K)
#define WSTRIDE 3080 // padded LDS row stride (bf16) -> row-to-row bank shift of 4
#define DTPB 512    // k_decode threads per block (8 waves -> 2 waves/SIMD)

typedef __attribute__((ext_vector_type(8))) __bf16 bf16x8;
typedef __attribute__((ext_vector_type(4))) __bf16 bf16x4;
typedef __attribute__((ext_vector_type(4))) float floatx4;
typedef __hip_bfloat16 bf16;

__device__ __forceinline__ float bf2f(bf16 x){ return __bfloat162float(x); }
__device__ __forceinline__ bf16 f2bf(float x){ return __float2bfloat16(x); }
__device__ __forceinline__ float sigm(float x){ return 1.0f/(1.0f+expf(-x)); }
// fast tanh: (e^{2x}-1)/(e^{2x}+1) via hardware exp + rcp. |err| ~1e-6,
// saturates correctly at +/-1.
__device__ __forceinline__ float fast_tanh(float x){
    float e2 = __expf(2.0f*x);
    return 1.0f - 2.0f*__builtin_amdgcn_rcpf(e2 + 1.0f);
}

// ---- dtype-adaptive load/store helpers (f=1: data is f32; f=0: bf16) ------
__device__ __forceinline__ float ld1(const void* base, size_t idx, int f){
    if (f) return ((const float*)base)[idx];
    return bf2f(((const bf16*)base)[idx]);
}
__device__ __forceinline__ bf16x8 ldbf8(const void* base, size_t idx, int f){
    if (f){
        const float* p = (const float*)base + idx;
        float4 a = *(const float4*)p, b = *(const float4*)(p+4);
        bf16x8 r;
        r[0]=(__bf16)a.x; r[1]=(__bf16)a.y; r[2]=(__bf16)a.z; r[3]=(__bf16)a.w;
        r[4]=(__bf16)b.x; r[5]=(__bf16)b.y; r[6]=(__bf16)b.z; r[7]=(__bf16)b.w;
        return r;
    }
    return *(const bf16x8*)((const bf16*)base + idx);
}
__device__ __forceinline__ bf16x8 bf8_of_f32(const float* p){
    float4 a = *(const float4*)p, b = *(const float4*)(p+4);
    bf16x8 r;
    r[0]=(__bf16)a.x; r[1]=(__bf16)a.y; r[2]=(__bf16)a.z; r[3]=(__bf16)a.w;
    r[4]=(__bf16)b.x; r[5]=(__bf16)b.y; r[6]=(__bf16)b.z; r[7]=(__bf16)b.w;
    return r;
}
__device__ __forceinline__ void st1(void* base, size_t idx, float v, int f){
    if (f) ((float*)base)[idx] = v;
    else   ((bf16*)base)[idx] = f2bf(v);
}

#define MFMA16(a,b,c) __builtin_amdgcn_mfma_f32_16x16x32_bf16(a,b,c,0,0,0)
// Verified fragment layout (learn_hip m89/m91):
//   A: lane holds A[m=lane&15][k=(lane>>4)*8+j]   (row-major [M][K])
//   B: lane holds Bt[n=lane&15][k=(lane>>4)*8+j]  (row-major [N][K])
//   D: lane holds D[row=(lane>>4)*4+r][col=lane&15]

// ---- custom grid barrier: two-level epoch counter, agent-scope acq/rel ----
// bar[g*16] : per-group arrival counters (16 groups of 16 blocks, 64B apart)
// bar[256]  : root counter (16 adds per epoch)
// Monotonic epochs -> no counter reset, no reset race. Measured r1->r3:
// saves ~20us/barrier vs cg::grid.sync. Release on arrival RMW orders prior
// global stores; acquire fence on exit invalidates reader-side caches.
__device__ __forceinline__ void gbar(unsigned* bar, unsigned ep){
    __syncthreads();
    if (threadIdx.x == 0){
        unsigned tgt = ep*16u;
        unsigned* grp  = bar + ((blockIdx.x >> 4) << 4);
        unsigned* root = bar + 256;
        unsigned old = __hip_atomic_fetch_add(grp, 1u, __ATOMIC_ACQ_REL, __HIP_MEMORY_SCOPE_AGENT);
        if (old + 1u == tgt)
            __hip_atomic_fetch_add(root, 1u, __ATOMIC_ACQ_REL, __HIP_MEMORY_SCOPE_AGENT);
        while (__hip_atomic_load(root, __ATOMIC_RELAXED, __HIP_MEMORY_SCOPE_AGENT) < tgt)
            __builtin_amdgcn_s_sleep(2);
        __builtin_amdgcn_fence(__ATOMIC_ACQUIRE, "agent");
    }
    __syncthreads();
}

// ---------------- kernel 0: dtype detect + barrier zero --------------------
__global__ void k_detect(const void* emb, int* flag, unsigned* bar){
    int tid = threadIdx.x;
    __shared__ int bad;
    if (tid == 0) bad = 0;
    for (int i = tid; i < 512; i += 256) bar[i] = 0u;
    __syncthreads();
    const unsigned short* u = (const unsigned short*)emb;
    int local = 0;
    for (int i = tid; i < 4096; i += 256){
        int e = (u[i] >> 7) & 0xFF;
        if (e > 140) local = 1;           // |v| > 2^13: impossible for real data
    }
    if (local) bad = 1;
    __syncthreads();
    if (tid == 0) *flag = bad;
}

// ---------------- prep kernels: convert weights to bf16 once ---------------
// wcat[r][0..2559] = w_ih[r], wcat[r][2560..3071] = w_hh[r]   (r = gate*512+n)
__global__ void k_prep_gates(const void* w_ih, const void* w_hh, bf16* __restrict__ wcat,
                             const int* __restrict__ flag){
    int ff = *flag;
    int r = blockIdx.x, tid = threadIdx.x;
    for (int i = tid*8; i < KCAT; i += 2048){
        bf16x8 v;
        if (i + 8 <= EIN){
            v = ldbf8(w_ih, (size_t)r*EIN + i, ff);
        } else if (i >= EIN){
            v = ldbf8(w_hh, (size_t)r*HD + (i - EIN), ff);
        } else {
#pragma unroll
            for (int j = 0; j < 8; ++j){
                int k = i + j;
                v[j] = (__bf16)((k < EIN) ? ld1(w_ih, (size_t)r*EIN + k, ff)
                                          : ld1(w_hh, (size_t)r*HD + (k - EIN), ff));
            }
        }
        *(bf16x8*)(wcat + (size_t)r*KCAT + i) = v;
    }
}
// vectorized convert, n must be divisible by 8
__global__ void k_prep_cvt8(const void* src, bf16* __restrict__ dst, size_t n8,
                            const int* __restrict__ flag){
    int ff = *flag;
    size_t idx = (size_t)blockIdx.x*256 + threadIdx.x;
    size_t stride = (size_t)gridDim.x*256;
    for (size_t i = idx; i < n8; i += stride)
        *(bf16x8*)(dst + i*8) = ldbf8(src, i*8, ff);
}

// ---------------- kernel 1: mean over feature positions (f32 out) ----------
__global__ void k_mean(const void* feat, float* __restrict__ mean_f,
                       const int* __restrict__ flag){
    int ff = *flag;
    int b = blockIdx.x, tid = threadIdx.x;
    for (int i = 0; i < ENC/256; ++i){
        int e = i*256 + tid;
        size_t base = (size_t)b*NF*ENC + e;
        float s = 0.f;
        for (int n = 0; n < NF; ++n) s += ld1(feat, base + (size_t)n*ENC, ff);
        mean_f[b*ENC + e] = s * (1.0f/49.0f);
    }
}

// ---------------- kernel 2: h0/c0 = mean_f @ [ihw|icw]^T + b (MFMA) --------
__global__ void k_init_hc(const float* __restrict__ mean_f,
                          const void* ihw, const void* ihb,
                          const void* icw, const void* icb,
                          float* __restrict__ Hbuf, float* __restrict__ c_f32,
                          const int* __restrict__ flag){
    int ff = *flag;
    int tid = threadIdx.x, wave = tid>>6, lane = tid&63, quad = lane>>4, lq = lane&15;
    int n0 = blockIdx.x*16;
    int ng = n0 + lq;
    const void* w = (ng < HD) ? ihw : icw;
    size_t wrow = (size_t)(ng < HD ? ng : ng - HD)*ENC;
    floatx4 acc[2] = {{0,0,0,0},{0,0,0,0}};
    int kb = wave*512;
    for (int kk = 0; kk < 16; ++kk){
        int k = kb + kk*32 + quad*8;
        bf16x8 bfr = ldbf8(w, wrow + k, ff);
#pragma unroll
        for (int mt = 0; mt < 2; ++mt){
            bf16x8 afr = bf8_of_f32(mean_f + (size_t)(mt*16+lq)*ENC + k);
            acc[mt] = MFMA16(afr, bfr, acc[mt]);
        }
    }
    __shared__ float red[4][2][16][16];
#pragma unroll
    for (int mt = 0; mt < 2; ++mt)
        for (int r = 0; r < 4; ++r)
            red[wave][mt][quad*4+r][lq] = acc[mt][r];
    __syncthreads();
    for (int rep = 0; rep < 2; ++rep){
        int idx = rep*256 + tid;
        int mt = idx>>8, mm = (idx>>4)&15, nn = idx&15;
        float v = red[0][mt][mm][nn]+red[1][mt][mm][nn]+red[2][mt][mm][nn]+red[3][mt][mm][nn];
        int n_g = n0 + nn, b = mt*16 + mm;
        if (n_g < HD) Hbuf[b*HD + n_g]        = v + ld1(ihb, n_g, ff);
        else          c_f32[b*HD + (n_g-HD)]  = v + ld1(icb, n_g - HD, ff);
    }
}

// ---------------- kernel 3: u_hs = feat_bf @ U_w^T + U_b (MFMA, f32 out) ---
__global__ void k_uhs(const bf16* __restrict__ feat_bf, const void* U_w, const void* U_b,
                      float* __restrict__ u_hs, const int* __restrict__ flag){
    int ff = *flag;
    int tid = threadIdx.x, wave = tid>>6, lane = tid&63, quad = lane>>4, lq = lane&15;
    int m0 = blockIdx.x*16;
    int n0 = blockIdx.y*64 + wave*16;
    size_t arow = (size_t)(m0+lq)*ENC;
    size_t brow = (size_t)(n0+lq)*ENC;
    floatx4 acc = {0,0,0,0};
    for (int kk = 0; kk < ENC/32; ++kk){
        int k = kk*32 + quad*8;
        bf16x8 afr = *(const bf16x8*)(feat_bf + arow + k);
        bf16x8 bfr = ldbf8(U_w,  brow + k, ff);
        acc = MFMA16(afr, bfr, acc);
    }
    float ub = ld1(U_b, n0+lq, ff);
    for (int r = 0; r < 4; ++r){
        int m = m0 + quad*4 + r;
        u_hs[(size_t)m*ATTD + n0 + lq] = acc[r] + ub;
    }
}

// ---------------- kernel 4: persistent cooperative decode loop -------------
// Grid 256 x 512 threads (8 waves/CU = 2/SIMD: TLP to hide L2 latency in
// phase A — r3 showed 1 wave/SIMD left attention ~80% stalled).
// Block bid owns hidden cols {2*bid, 2*bid+1}: its 8 wcat rows live in LDS
// for the whole loop; its c state lives in LDS.
// Per step: phase A (blocks 0..31 = batch) attention -> lstm_in[emb|ctx];
// gbar; phase B (waves 0-3 of all blocks) gates MFMA + LSTM pointwise; gbar.
__global__ void __launch_bounds__(DTPB) k_decode(
        float* __restrict__ Hbuf, const float* __restrict__ c0_f32,
        const bf16* __restrict__ Ww_bf, const void* __restrict__ W_b,
        const float* __restrict__ u_hs, const void* __restrict__ A_w,
        const void* __restrict__ A_b, const int* __restrict__ captions,
        const void* __restrict__ emb, const bf16* __restrict__ feat_bf,
        bf16* __restrict__ lstm_in, const bf16* __restrict__ wcat,
        const void* __restrict__ b_ih, const void* __restrict__ b_hh,
        bf16* __restrict__ Hall_bf, void* __restrict__ d_out,
        const int* __restrict__ flag, unsigned* __restrict__ bar)
{
    const int ff = *flag;
    const int bid = blockIdx.x, tid = threadIdx.x;
    const int wave = tid>>6, lane = tid&63, quad = lane>>4, lq = lane&15;

    __shared__ bf16  wlds[8*WSTRIDE];   // 49.28 KB: this block's 8 wcat rows
    __shared__ float ubuf[2048];        // 8 KB: attention scratch UNION mfma red
    __shared__ float aw_s[ATTD];        // 2 KB (attention blocks only)
    __shared__ float c_loc[64];         // persistent c state (32 b x 2 cols)
    __shared__ float gbias[8];          // b_ih+b_hh for this block's 8 rows

    // ---- prologue: load persistent state ----
    for (int n = 0; n < 8; ++n){
        int g = n>>1, j = n&1;
        const bf16* src = wcat + (size_t)(g*HD + (bid<<1) + j)*KCAT;
        for (int c8 = tid; c8 < KCAT/8; c8 += DTPB)
            *(bf16x8*)(wlds + n*WSTRIDE + c8*8) = *(const bf16x8*)(src + c8*8);
    }
    if (tid < 64){
        int bb = tid&31, j = tid>>5, col = (bid<<1)+j;
        c_loc[bb*2+j] = c0_f32[bb*HD + col];
        // h-section of lstm_in for t=0 (h0 from Hbuf slot 0)
        lstm_in[(size_t)bb*KCAT + EIN + col] = f2bf(Hbuf[bb*HD + col]);
    }
    if (tid < 8){
        int g = tid>>1, j = tid&1, col = (bid<<1)+j;
        gbias[tid] = ld1(b_ih, g*HD+col, ff) + ld1(b_hh, g*HD+col, ff);
    }
    if (bid < BB)
        for (int i = tid; i < ATTD; i += DTPB) aw_s[i] = ld1(A_w, i, ff);
    __syncthreads();

    // union views of ubuf (phase A scratch vs phase B reduce — never live
    // at the same time; gbar + __syncthreads order every transition)
    float* h_sh    = ubuf;          // [512]
    float* wah_s   = ubuf + 512;    // [512]
    float* sc_s    = ubuf + 1024;   // [52]
    float* alpha_s = ubuf + 1088;   // [52]
    float (*red)[2][16][16] = (float (*)[2][16][16])ubuf;  // [4][2][16][16]

    unsigned ep = 0;

    for (int t = 0; t < TSTEPS; ++t){
        // ===== phase A: attention (one block per batch b) =====
        if (bid < BB){
            const int b = bid;
            const float* h_t = Hbuf + (size_t)t*BB*HD;
            for (int i = tid; i < HD; i += DTPB) h_sh[i] = h_t[b*HD + i];
            int cap = captions[b*21 + t];
            for (int e = tid; e < EMB; e += DTPB)
                lstm_in[(size_t)b*KCAT + e] = f2bf(ld1(emb, (size_t)cap*EMB + e, ff));
            __syncthreads();
            // w_ah[a] = h . W_w[a] + W_b[a]  (1 row/thread, 4 split accs to
            // cut the serial FMA chain 4x)
            for (int a = tid; a < ATTD; a += DTPB){
                const bf16* wr = Ww_bf + (size_t)a*HD;
                float s0=0.f, s1=0.f, s2=0.f, s3=0.f;
                for (int k = 0; k < HD; k += 8){
                    bf16x8 wv = *(const bf16x8*)(wr + k);
                    s0 += (float)wv[0]*h_sh[k+0] + (float)wv[4]*h_sh[k+4];
                    s1 += (float)wv[1]*h_sh[k+1] + (float)wv[5]*h_sh[k+5];
                    s2 += (float)wv[2]*h_sh[k+2] + (float)wv[6]*h_sh[k+6];
                    s3 += (float)wv[3]*h_sh[k+3] + (float)wv[7]*h_sh[k+7];
                }
                wah_s[a] = ((s0+s1)+(s2+s3)) + ld1(W_b, a, ff);
            }
            __syncthreads();
            // scores[n] = A_w . tanh(u_hs[b,n,:] + w_ah) + A_b  (8 waves)
            {
                int a0 = lane*8;
                for (int n = wave; n < NF; n += 8){
                    const float* up = u_hs + (size_t)(b*NF + n)*ATTD + a0;
                    float4 u0 = *(const float4*)up;
                    float4 u1 = *(const float4*)(up + 4);
                    float p0 = fast_tanh(u0.x + wah_s[a0+0])*aw_s[a0+0]
                             + fast_tanh(u0.y + wah_s[a0+1])*aw_s[a0+1]
                             + fast_tanh(u0.z + wah_s[a0+2])*aw_s[a0+2]
                             + fast_tanh(u0.w + wah_s[a0+3])*aw_s[a0+3];
                    float p1 = fast_tanh(u1.x + wah_s[a0+4])*aw_s[a0+4]
                             + fast_tanh(u1.y + wah_s[a0+5])*aw_s[a0+5]
                             + fast_tanh(u1.z + wah_s[a0+6])*aw_s[a0+6]
                             + fast_tanh(u1.w + wah_s[a0+7])*aw_s[a0+7];
                    float p = p0 + p1;
                    for (int off = 32; off; off >>= 1) p += __shfl_down(p, off);
                    if (lane == 0) sc_s[n] = p + ld1(A_b, 0, ff);
                }
            }
            __syncthreads();
            // softmax over 49 (wave 0) + alpha output
            if (wave == 0){
                float v = (lane < NF) ? sc_s[lane] : -1e30f;
                float mx = v;
                for (int off = 32; off; off >>= 1) mx = fmaxf(mx, __shfl_down(mx, off));
                mx = __shfl(mx, 0);
                float e = (lane < NF) ? expf(v - mx) : 0.f;
                float s = e;
                for (int off = 32; off; off >>= 1) s += __shfl_down(s, off);
                s = __shfl(s, 0);
                if (lane < NF){
                    float al = e / s;
                    alpha_s[lane] = al;
                    st1(d_out, (size_t)BB*TSTEPS*VCB + (size_t)b*(TSTEPS*NF) + t*NF + lane, al, ff);
                }
            }
            __syncthreads();
            // context[e] = sum_n alpha[n]*feat_bf[b,n,e]; thread owns 4 contig e
            {
                int e0 = tid*4;
                float acc[4] = {0,0,0,0};
#pragma unroll 7
                for (int n = 0; n < NF; ++n){
                    float al = alpha_s[n];
                    bf16x4 v = *(const bf16x4*)(feat_bf + (size_t)b*NF*ENC + (size_t)n*ENC + e0);
#pragma unroll
                    for (int j = 0; j < 4; ++j) acc[j] += al*(float)v[j];
                }
                bf16x4 st;
#pragma unroll
                for (int j = 0; j < 4; ++j) st[j] = (__bf16)acc[j];
                *(bf16x4*)(lstm_in + (size_t)b*KCAT + EMB + e0) = st;
            }
        }
        gbar(bar, ++ep);

        // ===== phase B: gates MFMA (LDS wcat, waves 0-3) + LSTM pointwise ===
        if (wave < 4){
            int kb = wave*768;                      // K split 4x768 over waves
            floatx4 acc0 = {0,0,0,0}, acc1 = {0,0,0,0};
            const bf16* wrow = wlds + (size_t)(lq&7)*WSTRIDE;  // lanes 8..15 dup row (broadcast)
            const bf16* ar0 = lstm_in + (size_t)lq*KCAT;
            const bf16* ar1 = lstm_in + (size_t)(16+lq)*KCAT;
#pragma unroll
            for (int kk = 0; kk < 24; ++kk){
                int k = kb + kk*32 + quad*8;
                bf16x8 bfr = *(const bf16x8*)(wrow + k);
                acc0 = MFMA16(*(const bf16x8*)(ar0 + k), bfr, acc0);
                acc1 = MFMA16(*(const bf16x8*)(ar1 + k), bfr, acc1);
            }
#pragma unroll
            for (int r = 0; r < 4; ++r){
                red[wave][0][quad*4+r][lq] = acc0[r];
                red[wave][1][quad*4+r][lq] = acc1[r];
            }
        }
        __syncthreads();
        if (tid < 64){
            int bb = tid&31, j = tid>>5;
            int mt = bb>>4, mm = bb&15;
            float G[4];
#pragma unroll
            for (int g = 0; g < 4; ++g){
                int n = g*2 + j;                    // B-row n = gate*2 + col
                G[g] = red[0][mt][mm][n] + red[1][mt][mm][n]
                     + red[2][mt][mm][n] + red[3][mt][mm][n] + gbias[n];
            }
            float c_old = c_loc[bb*2+j];
            float c_new = sigm(G[1])*c_old + sigm(G[0])*tanhf(G[2]);
            float h_new = sigm(G[3])*tanhf(c_new);
            c_loc[bb*2+j] = c_new;
            int col = (bid<<1)+j;
            Hbuf[(size_t)(t+1)*BB*HD + bb*HD + col] = h_new;
            Hall_bf[(size_t)t*BB*HD + bb*HD + col]  = f2bf(h_new);
            lstm_in[(size_t)bb*KCAT + EIN + col]    = f2bf(h_new);
        }
        gbar(bar, ++ep);
    }
}

// ---------------- kernel 6: preds = Hall_bf @ fcnw_bf^T + fcn_b ------------
__global__ void __launch_bounds__(256) k_fcn(const bf16* __restrict__ Hall_bf,
                                             const bf16* __restrict__ fcnw_bf,
                                             const void* fcn_b, void* d_out,
                                             const int* __restrict__ flag){
    int ff = *flag;
    int tid = threadIdx.x, wave = tid>>6, lane = tid&63, quad = lane>>4, lq = lane&15;
    int n0 = blockIdx.x*64 + wave*16;
    int v = n0 + lq;
    int vc = (v < VCB) ? v : (VCB-1);
    const bf16* brow = fcnw_bf + (size_t)vc*HD;
    bf16x8 bfr[16];
#pragma unroll
    for (int kk = 0; kk < 16; ++kk) bfr[kk] = *(const bf16x8*)(brow + kk*32 + quad*8);
    float bias = ld1(fcn_b, vc, ff);
    for (int mt = 0; mt < 40; ++mt){
        const bf16* arow = Hall_bf + (size_t)(mt*16 + lq)*HD;
        floatx4 acc = {0,0,0,0};
#pragma unroll
        for (int kk = 0; kk < 16; ++kk){
            bf16x8 afr = *(const bf16x8*)(arow + kk*32 + quad*8);
            acc = MFMA16(afr, bfr[kk], acc);
        }
        if (v < VCB){
#pragma unroll
            for (int r = 0; r < 4; ++r){
                int m = mt*16 + quad*4 + r;
                int b = m & 31, tt = m >> 5;
                st1(d_out, (size_t)b*(TSTEPS*VCB) + (size_t)tt*VCB + v, acc[r] + bias, ff);
            }
        }
    }
}

// ---------------- host launch ---------------------------------------------
extern "C" void kernel_launch(void* const* d_in, const int* in_sizes, int n_in,
                              void* d_out, int out_size, void* d_ws, size_t ws_size,
                              hipStream_t stream) {
    const void* feat  = d_in[0];
    const int*  caps  = (const int*)d_in[1];
    const void* emb   = d_in[2];
    const void* W_w   = d_in[3];
    const void* W_b   = d_in[4];
    const void* U_w   = d_in[5];
    const void* U_b   = d_in[6];
    const void* A_w   = d_in[7];
    const void* A_b   = d_in[8];
    const void* ihw   = d_in[9];
    const void* ihb   = d_in[10];
    const void* icw   = d_in[11];
    const void* icb   = d_in[12];
    const void* w_ih  = d_in[13];
    const void* w_hh  = d_in[14];
    const void* b_ih  = d_in[15];
    const void* b_hh  = d_in[16];
    const void* fcn_w = d_in[17];
    const void* fcn_b = d_in[18];

    // workspace layout (16B-aligned)
    char* ws = (char*)d_ws;
    size_t off = 0;
    float* u_hs    = (float*)(ws + off); off += (size_t)BB*NF*ATTD*4;       // 3.2 MB
    float* c_f32   = (float*)(ws + off); off += (size_t)BB*HD*4;            // 64 KB
    float* mean_f  = (float*)(ws + off); off += (size_t)BB*ENC*4;           // 256 KB
    float* Hbuf    = (float*)(ws + off); off += (size_t)(TSTEPS+1)*BB*HD*4; // 1.38 MB
    bf16*  lstm_in = (bf16*) (ws + off); off += (size_t)BB*KCAT*2;          // 192 KB
    bf16*  Hall_bf = (bf16*) (ws + off); off += (size_t)TSTEPS*BB*HD*2;     // 640 KB
    bf16*  wcat    = (bf16*) (ws + off); off += (size_t)4*HD*KCAT*2;        // 12.6 MB
    bf16*  fcnw_bf = (bf16*) (ws + off); off += (size_t)VCB*HD*2;           // 31.25 MB
    bf16*  Ww_bf   = (bf16*) (ws + off); off += (size_t)ATTD*HD*2;          // 512 KB
    bf16*  feat_bf = (bf16*) (ws + off); off += (size_t)BB*NF*ENC*2;        // 6.4 MB
    int*   flag    = (int*)  (ws + off); off += 256;
    unsigned* bar  = (unsigned*)(ws + off); off += 2048;
    if (ws_size < off) return;

    k_detect    <<<1, 256, 0, stream>>>(emb, flag, bar);
    k_prep_gates<<<2048, 256, 0, stream>>>(w_ih, w_hh, wcat, flag);
    k_prep_cvt8 <<<2048, 256, 0, stream>>>(fcn_w, fcnw_bf, (size_t)VCB*HD/8, flag);
    k_prep_cvt8 <<<128, 256, 0, stream>>>(W_w, Ww_bf, (size_t)ATTD*HD/8, flag);
    k_prep_cvt8 <<<1024, 256, 0, stream>>>(feat, feat_bf, (size_t)BB*NF*ENC/8, flag);
    k_mean      <<<BB, 256, 0, stream>>>(feat, mean_f, flag);
    k_init_hc   <<<64, 256, 0, stream>>>(mean_f, ihw, ihb, icw, icb, Hbuf, c_f32, flag);
    k_uhs       <<<dim3(98, 8), 256, 0, stream>>>(feat_bf, U_w, U_b, u_hs, flag);

    // whole 20-step decode loop in one cooperative launch (2 custom barriers/step)
    {
        void* kargs[18] = {
            (void*)&Hbuf, (void*)&c_f32, (void*)&Ww_bf, (void*)&W_b,
            (void*)&u_hs, (void*)&A_w, (void*)&A_b, (void*)&caps,
            (void*)&emb, (void*)&feat_bf, (void*)&lstm_in, (void*)&wcat,
            (void*)&b_ih, (void*)&b_hh, (void*)&Hall_bf, (void*)&d_out,
            (void*)&flag, (void*)&bar
        };
        hipLaunchCooperativeKernel((void*)k_decode, dim3(256), dim3(DTPB),
                                   kargs, 0, stream);
    }

    k_fcn<<<477, 256, 0, stream>>>(Hall_bf, fcnw_bf, fcn_b, d_out, flag);
}

// Round 5
// 1549.950 us; speedup vs baseline: 1.0639x; 1.0639x over previous
//
#include <hip/hip_runtime.h>
#include <hip/hip_bf16.h>

// Problem constants (bert-base captioning decoder)
#define VCB 30522   // vocab
#define EMB 512     // embed size
#define ATTD 512    // attention dim
#define ENC 2048    // encoder dim
#define HD 512      // hidden dim
#define BB 32       // batch
#define NF 49       // image features
#define TSTEPS 20   // decode steps
#define EIN 2560    // EMB + ENC (lstm input)
#define KCAT 3072   // EIN + HD (fused gate GEMM K)
#define WSTRIDE 3080 // padded LDS row stride (bf16) -> row-to-row bank shift of 4
#define DTPB 512    // k_decode threads per block (8 waves)
#define NBLK 128    // k_decode blocks: each owns 4 hidden cols (16 wcat rows)
#define NGRP 8      // barrier groups (16 blocks each)

typedef __attribute__((ext_vector_type(8))) __bf16 bf16x8;
typedef __attribute__((ext_vector_type(4))) __bf16 bf16x4;
typedef __attribute__((ext_vector_type(4))) float floatx4;
typedef __hip_bfloat16 bf16;

__device__ __forceinline__ float bf2f(bf16 x){ return __bfloat162float(x); }
__device__ __forceinline__ bf16 f2bf(float x){ return __float2bfloat16(x); }
__device__ __forceinline__ float sigm(float x){ return 1.0f/(1.0f+expf(-x)); }
// fast tanh: (e^{2x}-1)/(e^{2x}+1) via hardware exp + rcp. |err| ~1e-6.
__device__ __forceinline__ float fast_tanh(float x){
    float e2 = __expf(2.0f*x);
    return 1.0f - 2.0f*__builtin_amdgcn_rcpf(e2 + 1.0f);
}

// ---- coherent (Infinity-Cache point) relaxed dword access -----------------
// Relaxed agent-scope atomics compile to sc1 loads/stores that bypass the
// non-coherent per-XCD L2s and operate at the coherent MALL — NO fences,
// NO buffer_wbl2/inv (r4 post-mortem: those fences were ~24us/barrier).
__device__ __forceinline__ unsigned coh_ld(const unsigned* p){
    return __hip_atomic_load(p, __ATOMIC_RELAXED, __HIP_MEMORY_SCOPE_AGENT);
}
__device__ __forceinline__ void coh_st(unsigned* p, unsigned v){
    __hip_atomic_store(p, v, __ATOMIC_RELAXED, __HIP_MEMORY_SCOPE_AGENT);
}
__device__ __forceinline__ unsigned pack2bf(float a, float b){
    unsigned short ua = __builtin_bit_cast(unsigned short, f2bf(a));
    unsigned short ub = __builtin_bit_cast(unsigned short, f2bf(b));
    return (unsigned)ua | ((unsigned)ub << 16);
}

// ---- dtype-adaptive load/store helpers (f=1: data is f32; f=0: bf16) ------
__device__ __forceinline__ float ld1(const void* base, size_t idx, int f){
    if (f) return ((const float*)base)[idx];
    return bf2f(((const bf16*)base)[idx]);
}
__device__ __forceinline__ bf16x8 ldbf8(const void* base, size_t idx, int f){
    if (f){
        const float* p = (const float*)base + idx;
        float4 a = *(const float4*)p, b = *(const float4*)(p+4);
        bf16x8 r;
        r[0]=(__bf16)a.x; r[1]=(__bf16)a.y; r[2]=(__bf16)a.z; r[3]=(__bf16)a.w;
        r[4]=(__bf16)b.x; r[5]=(__bf16)b.y; r[6]=(__bf16)b.z; r[7]=(__bf16)b.w;
        return r;
    }
    return *(const bf16x8*)((const bf16*)base + idx);
}
__device__ __forceinline__ bf16x8 bf8_of_f32(const float* p){
    float4 a = *(const float4*)p, b = *(const float4*)(p+4);
    bf16x8 r;
    r[0]=(__bf16)a.x; r[1]=(__bf16)a.y; r[2]=(__bf16)a.z; r[3]=(__bf16)a.w;
    r[4]=(__bf16)b.x; r[5]=(__bf16)b.y; r[6]=(__bf16)b.z; r[7]=(__bf16)b.w;
    return r;
}
__device__ __forceinline__ void st1(void* base, size_t idx, float v, int f){
    if (f) ((float*)base)[idx] = v;
    else   ((bf16*)base)[idx] = f2bf(v);
}

#define MFMA16(a,b,c) __builtin_amdgcn_mfma_f32_16x16x32_bf16(a,b,c,0,0,0)
// Verified fragment layout (learn_hip m89/m91):
//   A: lane holds A[m=lane&15][k=(lane>>4)*8+j]   (row-major [M][K])
//   B: lane holds Bt[n=lane&15][k=(lane>>4)*8+j]  (row-major [N][K])
//   D: lane holds D[row=(lane>>4)*4+r][col=lane&15]

// ---- custom grid barrier: two-level epoch counter, RELAXED-only -----------
// bar[g*16] : per-group arrival counters (NGRP groups of 16 blocks, 64B apart)
// bar[256]  : root counter (NGRP adds per epoch). Monotonic epochs.
// No fences at all: __syncthreads drains vmcnt(0) (prior sc1 stores reach the
// coherent point before the arrival add issues); readers' subsequent sc1
// loads are issued in-order after the poll, and __syncthreads is the
// compiler barrier.
__device__ __forceinline__ void gbar(unsigned* bar, unsigned ep){
    __syncthreads();
    if (threadIdx.x == 0){
        unsigned* grp  = bar + ((blockIdx.x >> 4) << 4);
        unsigned* root = bar + 256;
        unsigned old = __hip_atomic_fetch_add(grp, 1u, __ATOMIC_RELAXED, __HIP_MEMORY_SCOPE_AGENT);
        if (old + 1u == ep*16u)
            __hip_atomic_fetch_add(root, 1u, __ATOMIC_RELAXED, __HIP_MEMORY_SCOPE_AGENT);
        while (__hip_atomic_load(root, __ATOMIC_RELAXED, __HIP_MEMORY_SCOPE_AGENT) < ep*NGRP)
            __builtin_amdgcn_s_sleep(2);
    }
    __syncthreads();
}

// ---------------- kernel 0: dtype detect + barrier zero --------------------
__global__ void k_detect(const void* emb, int* flag, unsigned* bar){
    int tid = threadIdx.x;
    __shared__ int bad;
    if (tid == 0) bad = 0;
    for (int i = tid; i < 512; i += 256) bar[i] = 0u;
    __syncthreads();
    const unsigned short* u = (const unsigned short*)emb;
    int local = 0;
    for (int i = tid; i < 4096; i += 256){
        int e = (u[i] >> 7) & 0xFF;
        if (e > 140) local = 1;           // |v| > 2^13: impossible for real data
    }
    if (local) bad = 1;
    __syncthreads();
    if (tid == 0) *flag = bad;
}

// ---------------- prep kernels: convert weights to bf16 once ---------------
// wcat[r][0..2559] = w_ih[r], wcat[r][2560..3071] = w_hh[r]   (r = gate*512+n)
__global__ void k_prep_gates(const void* w_ih, const void* w_hh, bf16* __restrict__ wcat,
                             const int* __restrict__ flag){
    int ff = *flag;
    int r = blockIdx.x, tid = threadIdx.x;
    for (int i = tid*8; i < KCAT; i += 2048){
        bf16x8 v;
        if (i + 8 <= EIN){
            v = ldbf8(w_ih, (size_t)r*EIN + i, ff);
        } else if (i >= EIN){
            v = ldbf8(w_hh, (size_t)r*HD + (i - EIN), ff);
        } else {
#pragma unroll
            for (int j = 0; j < 8; ++j){
                int k = i + j;
                v[j] = (__bf16)((k < EIN) ? ld1(w_ih, (size_t)r*EIN + k, ff)
                                          : ld1(w_hh, (size_t)r*HD + (k - EIN), ff));
            }
        }
        *(bf16x8*)(wcat + (size_t)r*KCAT + i) = v;
    }
}
// vectorized convert, n must be divisible by 8
__global__ void k_prep_cvt8(const void* src, bf16* __restrict__ dst, size_t n8,
                            const int* __restrict__ flag){
    int ff = *flag;
    size_t idx = (size_t)blockIdx.x*256 + threadIdx.x;
    size_t stride = (size_t)gridDim.x*256;
    for (size_t i = idx; i < n8; i += stride)
        *(bf16x8*)(dst + i*8) = ldbf8(src, i*8, ff);
}

// ---------------- kernel 1: mean over feature positions (f32 out) ----------
__global__ void k_mean(const void* feat, float* __restrict__ mean_f,
                       const int* __restrict__ flag){
    int ff = *flag;
    int b = blockIdx.x, tid = threadIdx.x;
    for (int i = 0; i < ENC/256; ++i){
        int e = i*256 + tid;
        size_t base = (size_t)b*NF*ENC + e;
        float s = 0.f;
        for (int n = 0; n < NF; ++n) s += ld1(feat, base + (size_t)n*ENC, ff);
        mean_f[b*ENC + e] = s * (1.0f/49.0f);
    }
}

// ---------------- kernel 2: h0/c0 = mean_f @ [ihw|icw]^T + b (MFMA) --------
__global__ void k_init_hc(const float* __restrict__ mean_f,
                          const void* ihw, const void* ihb,
                          const void* icw, const void* icb,
                          float* __restrict__ Hbuf, float* __restrict__ c_f32,
                          const int* __restrict__ flag){
    int ff = *flag;
    int tid = threadIdx.x, wave = tid>>6, lane = tid&63, quad = lane>>4, lq = lane&15;
    int n0 = blockIdx.x*16;
    int ng = n0 + lq;
    const void* w = (ng < HD) ? ihw : icw;
    size_t wrow = (size_t)(ng < HD ? ng : ng - HD)*ENC;
    floatx4 acc[2] = {{0,0,0,0},{0,0,0,0}};
    int kb = wave*512;
    for (int kk = 0; kk < 16; ++kk){
        int k = kb + kk*32 + quad*8;
        bf16x8 bfr = ldbf8(w, wrow + k, ff);
#pragma unroll
        for (int mt = 0; mt < 2; ++mt){
            bf16x8 afr = bf8_of_f32(mean_f + (size_t)(mt*16+lq)*ENC + k);
            acc[mt] = MFMA16(afr, bfr, acc[mt]);
        }
    }
    __shared__ float red[4][2][16][16];
#pragma unroll
    for (int mt = 0; mt < 2; ++mt)
        for (int r = 0; r < 4; ++r)
            red[wave][mt][quad*4+r][lq] = acc[mt][r];
    __syncthreads();
    for (int rep = 0; rep < 2; ++rep){
        int idx = rep*256 + tid;
        int mt = idx>>8, mm = (idx>>4)&15, nn = idx&15;
        float v = red[0][mt][mm][nn]+red[1][mt][mm][nn]+red[2][mt][mm][nn]+red[3][mt][mm][nn];
        int n_g = n0 + nn, b = mt*16 + mm;
        if (n_g < HD) Hbuf[b*HD + n_g]        = v + ld1(ihb, n_g, ff);
        else          c_f32[b*HD + (n_g-HD)]  = v + ld1(icb, n_g - HD, ff);
    }
}

// ---------------- kernel 3: u_hs = feat_bf @ U_w^T + U_b (MFMA, f32 out) ---
__global__ void k_uhs(const bf16* __restrict__ feat_bf, const void* U_w, const void* U_b,
                      float* __restrict__ u_hs, const int* __restrict__ flag){
    int ff = *flag;
    int tid = threadIdx.x, wave = tid>>6, lane = tid&63, quad = lane>>4, lq = lane&15;
    int m0 = blockIdx.x*16;
    int n0 = blockIdx.y*64 + wave*16;
    size_t arow = (size_t)(m0+lq)*ENC;
    size_t brow = (size_t)(n0+lq)*ENC;
    floatx4 acc = {0,0,0,0};
    for (int kk = 0; kk < ENC/32; ++kk){
        int k = kk*32 + quad*8;
        bf16x8 afr = *(const bf16x8*)(feat_bf + arow + k);
        bf16x8 bfr = ldbf8(U_w,  brow + k, ff);
        acc = MFMA16(afr, bfr, acc);
    }
    float ub = ld1(U_b, n0+lq, ff);
    for (int r = 0; r < 4; ++r){
        int m = m0 + quad*4 + r;
        u_hs[(size_t)m*ATTD + n0 + lq] = acc[r] + ub;
    }
}

// ---------------- kernel 4: persistent cooperative decode loop -------------
// Grid 128 x 512 threads. Block bid owns hidden cols {4bid..4bid+3}: its 16
// wcat rows (4 gates x 4 cols, 98.5 KB) live in LDS for the whole loop; its
// c state lives in LDS. Cross-block data (lstm_in, Hbuf) flows through
// relaxed agent-scope (sc1, MALL-coherent) dword accesses — no fences.
// Per step: phase A (blocks 0..31 = batch) attention -> lstm_in[emb|ctx];
// gbar; phase B (waves 0-3) gates MFMA + LSTM pointwise -> h,c; gbar.
__global__ void __launch_bounds__(DTPB) k_decode(
        float* __restrict__ Hbuf, const float* __restrict__ c0_f32,
        const bf16* __restrict__ Ww_bf, const void* __restrict__ W_b,
        const float* __restrict__ u_hs, const void* __restrict__ A_w,
        const void* __restrict__ A_b, const int* __restrict__ captions,
        const void* __restrict__ emb, const bf16* __restrict__ feat_bf,
        bf16* __restrict__ lstm_in, const bf16* __restrict__ wcat,
        const void* __restrict__ b_ih, const void* __restrict__ b_hh,
        bf16* __restrict__ Hall_bf, void* __restrict__ d_out,
        const int* __restrict__ flag, unsigned* __restrict__ bar)
{
    const int ff = *flag;
    const int bid = blockIdx.x, tid = threadIdx.x;
    const int wave = tid>>6, lane = tid&63, quad = lane>>4, lq = lane&15;

    __shared__ bf16  wlds[16*WSTRIDE];  // 98.56 KB: this block's 16 wcat rows
    __shared__ float ubuf[2048];        // 8 KB: attention scratch UNION mfma red
    __shared__ float aw_s[ATTD];        // 2 KB (attention blocks only)
    __shared__ float c_loc[BB*4];       // persistent c state (32 b x 4 cols)
    __shared__ float gbias[16];         // b_ih+b_hh for this block's 16 rows

    unsigned* lin_u = (unsigned*)lstm_in;     // lstm_in as dwords (bf16 pairs)

    // ---- prologue: load persistent state ----
    for (int n = 0; n < 16; ++n){
        int g = n>>2, j = n&3;
        const bf16* src = wcat + (size_t)(g*HD + (bid<<2) + j)*KCAT;
        for (int c8 = tid; c8 < KCAT/8; c8 += DTPB)
            *(bf16x8*)(wlds + n*WSTRIDE + c8*8) = *(const bf16x8*)(src + c8*8);
    }
    if (tid < 128){
        int bb = tid&31, j = tid>>5, col = (bid<<2)+j;
        c_loc[bb*4+j] = c0_f32[bb*HD + col];   // plain: pre-kernel data
    }
    if (tid < 64){
        // h-section of lstm_in for t=0 (h0 from Hbuf slot 0), dword-packed
        int bb = tid&31, j2 = tid>>5;
        int c0 = (bid<<2) + 2*j2;
        float h0 = Hbuf[bb*HD + c0], h1 = Hbuf[bb*HD + c0 + 1];
        coh_st(lin_u + (size_t)bb*(KCAT/2) + (EIN + c0)/2, pack2bf(h0, h1));
    }
    if (tid < 16){
        int g = tid>>2, j = tid&3, col = (bid<<2)+j;
        gbias[tid] = ld1(b_ih, g*HD+col, ff) + ld1(b_hh, g*HD+col, ff);
    }
    if (bid < BB)
        for (int i = tid; i < ATTD; i += DTPB) aw_s[i] = ld1(A_w, i, ff);
    __syncthreads();

    // union views of ubuf (phase A scratch vs phase B reduce — never live
    // at the same time; gbar + __syncthreads order every transition)
    float* h_sh    = ubuf;          // [512]
    float* wah_s   = ubuf + 512;    // [512]
    float* sc_s    = ubuf + 1024;   // [52]
    float* alpha_s = ubuf + 1088;   // [52]
    float (*red)[2][16][16] = (float (*)[2][16][16])ubuf;  // [4][2][16][16]

    unsigned ep = 0;

    for (int t = 0; t < TSTEPS; ++t){
        // ===== phase A: attention (one block per batch b) =====
        if (bid < BB){
            const int b = bid;
            const unsigned* hrow = (const unsigned*)(Hbuf + (size_t)t*BB*HD + b*HD);
            for (int i = tid; i < HD; i += DTPB)
                h_sh[i] = __uint_as_float(coh_ld(hrow + i));
            int cap = captions[b*21 + t];
            for (int e2 = tid; e2 < EMB/2; e2 += DTPB){
                float a = ld1(emb, (size_t)cap*EMB + 2*e2,     ff);
                float c = ld1(emb, (size_t)cap*EMB + 2*e2 + 1, ff);
                coh_st(lin_u + (size_t)b*(KCAT/2) + e2, pack2bf(a, c));
            }
            __syncthreads();
            // w_ah[a] = h . W_w[a] + W_b[a]  (1 row/thread, 4 split accs)
            for (int a = tid; a < ATTD; a += DTPB){
                const bf16* wr = Ww_bf + (size_t)a*HD;
                float s0=0.f, s1=0.f, s2=0.f, s3=0.f;
                for (int k = 0; k < HD; k += 8){
                    bf16x8 wv = *(const bf16x8*)(wr + k);
                    s0 += (float)wv[0]*h_sh[k+0] + (float)wv[4]*h_sh[k+4];
                    s1 += (float)wv[1]*h_sh[k+1] + (float)wv[5]*h_sh[k+5];
                    s2 += (float)wv[2]*h_sh[k+2] + (float)wv[6]*h_sh[k+6];
                    s3 += (float)wv[3]*h_sh[k+3] + (float)wv[7]*h_sh[k+7];
                }
                wah_s[a] = ((s0+s1)+(s2+s3)) + ld1(W_b, a, ff);
            }
            __syncthreads();
            // scores[n] = A_w . tanh(u_hs[b,n,:] + w_ah) + A_b  (8 waves)
            {
                int a0 = lane*8;
                for (int n = wave; n < NF; n += 8){
                    const float* up = u_hs + (size_t)(b*NF + n)*ATTD + a0;
                    float4 u0 = *(const float4*)up;
                    float4 u1 = *(const float4*)(up + 4);
                    float p0 = fast_tanh(u0.x + wah_s[a0+0])*aw_s[a0+0]
                             + fast_tanh(u0.y + wah_s[a0+1])*aw_s[a0+1]
                             + fast_tanh(u0.z + wah_s[a0+2])*aw_s[a0+2]
                             + fast_tanh(u0.w + wah_s[a0+3])*aw_s[a0+3];
                    float p1 = fast_tanh(u1.x + wah_s[a0+4])*aw_s[a0+4]
                             + fast_tanh(u1.y + wah_s[a0+5])*aw_s[a0+5]
                             + fast_tanh(u1.z + wah_s[a0+6])*aw_s[a0+6]
                             + fast_tanh(u1.w + wah_s[a0+7])*aw_s[a0+7];
                    float p = p0 + p1;
                    for (int off = 32; off; off >>= 1) p += __shfl_down(p, off);
                    if (lane == 0) sc_s[n] = p + ld1(A_b, 0, ff);
                }
            }
            __syncthreads();
            // softmax over 49 (wave 0) + alpha output
            if (wave == 0){
                float v = (lane < NF) ? sc_s[lane] : -1e30f;
                float mx = v;
                for (int off = 32; off; off >>= 1) mx = fmaxf(mx, __shfl_down(mx, off));
                mx = __shfl(mx, 0);
                float e = (lane < NF) ? expf(v - mx) : 0.f;
                float s = e;
                for (int off = 32; off; off >>= 1) s += __shfl_down(s, off);
                s = __shfl(s, 0);
                if (lane < NF){
                    float al = e / s;
                    alpha_s[lane] = al;
                    st1(d_out, (size_t)BB*TSTEPS*VCB + (size_t)b*(TSTEPS*NF) + t*NF + lane, al, ff);
                }
            }
            __syncthreads();
            // context[e] = sum_n alpha[n]*feat_bf[b,n,e]; thread owns 4 contig e
            {
                int e0 = tid*4;
                float acc[4] = {0,0,0,0};
#pragma unroll 7
                for (int n = 0; n < NF; ++n){
                    float al = alpha_s[n];
                    bf16x4 v = *(const bf16x4*)(feat_bf + (size_t)b*NF*ENC + (size_t)n*ENC + e0);
#pragma unroll
                    for (int j = 0; j < 4; ++j) acc[j] += al*(float)v[j];
                }
                unsigned* lrow = lin_u + (size_t)b*(KCAT/2) + (EMB + e0)/2;
                coh_st(lrow,     pack2bf(acc[0], acc[1]));
                coh_st(lrow + 1, pack2bf(acc[2], acc[3]));
            }
        }
        gbar(bar, ++ep);

        // ===== phase B: gates MFMA (LDS wcat, waves 0-3) + LSTM pointwise ===
        if (wave < 4){
            int kb = wave*768;                      // K split 4x768 over waves
            floatx4 acc0 = {0,0,0,0}, acc1 = {0,0,0,0};
            const bf16* wrow = wlds + (size_t)lq*WSTRIDE;  // 16 distinct B-rows
            const unsigned* ar0 = lin_u + (size_t)lq*(KCAT/2);
            const unsigned* ar1 = lin_u + (size_t)(16+lq)*(KCAT/2);
            union U8 { unsigned u[4]; bf16x8 v; };
#pragma unroll
            for (int kk = 0; kk < 24; ++kk){
                int kd = (kb + kk*32 + quad*8) >> 1;   // dword index
                bf16x8 bfr = *(const bf16x8*)(wrow + kb + kk*32 + quad*8);
                U8 a0, a1;
#pragma unroll
                for (int q = 0; q < 4; ++q){
                    a0.u[q] = coh_ld(ar0 + kd + q);
                    a1.u[q] = coh_ld(ar1 + kd + q);
                }
                acc0 = MFMA16(a0.v, bfr, acc0);
                acc1 = MFMA16(a1.v, bfr, acc1);
            }
#pragma unroll
            for (int r = 0; r < 4; ++r){
                red[wave][0][quad*4+r][lq] = acc0[r];
                red[wave][1][quad*4+r][lq] = acc1[r];
            }
        }
        __syncthreads();
        if (tid < 64){
            int bb = tid&31, j2 = tid>>5;           // j2: col pair 0/1
            int mt = bb>>4, mm = bb&15;
            float hn[2];
#pragma unroll
            for (int sub = 0; sub < 2; ++sub){
                int j = 2*j2 + sub;                 // col-in-block 0..3
                float G[4];
#pragma unroll
                for (int g = 0; g < 4; ++g){
                    int n = g*4 + j;                // B-row n = gate*4 + col
                    G[g] = red[0][mt][mm][n] + red[1][mt][mm][n]
                         + red[2][mt][mm][n] + red[3][mt][mm][n] + gbias[n];
                }
                float c_old = c_loc[bb*4+j];
                float c_new = sigm(G[1])*c_old + sigm(G[0])*tanhf(G[2]);
                float h_new = sigm(G[3])*tanhf(c_new);
                c_loc[bb*4+j] = c_new;
                hn[sub] = h_new;
            }
            int colb = (bid<<2) + 2*j2;
            unsigned* hb = (unsigned*)(Hbuf + (size_t)(t+1)*BB*HD + bb*HD + colb);
            coh_st(hb,     __float_as_uint(hn[0]));
            coh_st(hb + 1, __float_as_uint(hn[1]));
            ((unsigned*)Hall_bf)[((size_t)t*BB*HD + bb*HD + colb) >> 1] = pack2bf(hn[0], hn[1]);
            coh_st(lin_u + (size_t)bb*(KCAT/2) + (EIN + colb)/2, pack2bf(hn[0], hn[1]));
        }
        gbar(bar, ++ep);
    }
}

// ---------------- kernel 6: preds = Hall_bf @ fcnw_bf^T + fcn_b ------------
__global__ void __launch_bounds__(256) k_fcn(const bf16* __restrict__ Hall_bf,
                                             const bf16* __restrict__ fcnw_bf,
                                             const void* fcn_b, void* d_out,
                                             const int* __restrict__ flag){
    int ff = *flag;
    int tid = threadIdx.x, wave = tid>>6, lane = tid&63, quad = lane>>4, lq = lane&15;
    int n0 = blockIdx.x*64 + wave*16;
    int v = n0 + lq;
    int vc = (v < VCB) ? v : (VCB-1);
    const bf16* brow = fcnw_bf + (size_t)vc*HD;
    bf16x8 bfr[16];
#pragma unroll
    for (int kk = 0; kk < 16; ++kk) bfr[kk] = *(const bf16x8*)(brow + kk*32 + quad*8);
    float bias = ld1(fcn_b, vc, ff);
    for (int mt = 0; mt < 40; ++mt){
        const bf16* arow = Hall_bf + (size_t)(mt*16 + lq)*HD;
        floatx4 acc = {0,0,0,0};
#pragma unroll
        for (int kk = 0; kk < 16; ++kk){
            bf16x8 afr = *(const bf16x8*)(arow + kk*32 + quad*8);
            acc = MFMA16(afr, bfr[kk], acc);
        }
        if (v < VCB){
#pragma unroll
            for (int r = 0; r < 4; ++r){
                int m = mt*16 + quad*4 + r;
                int b = m & 31, tt = m >> 5;
                st1(d_out, (size_t)b*(TSTEPS*VCB) + (size_t)tt*VCB + v, acc[r] + bias, ff);
            }
        }
    }
}

// ---------------- host launch ---------------------------------------------
extern "C" void kernel_launch(void* const* d_in, const int* in_sizes, int n_in,
                              void* d_out, int out_size, void* d_ws, size_t ws_size,
                              hipStream_t stream) {
    const void* feat  = d_in[0];
    const int*  caps  = (const int*)d_in[1];
    const void* emb   = d_in[2];
    const void* W_w   = d_in[3];
    const void* W_b   = d_in[4];
    const void* U_w   = d_in[5];
    const void* U_b   = d_in[6];
    const void* A_w   = d_in[7];
    const void* A_b   = d_in[8];
    const void* ihw   = d_in[9];
    const void* ihb   = d_in[10];
    const void* icw   = d_in[11];
    const void* icb   = d_in[12];
    const void* w_ih  = d_in[13];
    const void* w_hh  = d_in[14];
    const void* b_ih  = d_in[15];
    const void* b_hh  = d_in[16];
    const void* fcn_w = d_in[17];
    const void* fcn_b = d_in[18];

    // workspace layout (16B-aligned)
    char* ws = (char*)d_ws;
    size_t off = 0;
    float* u_hs    = (float*)(ws + off); off += (size_t)BB*NF*ATTD*4;       // 3.2 MB
    float* c_f32   = (float*)(ws + off); off += (size_t)BB*HD*4;            // 64 KB
    float* mean_f  = (float*)(ws + off); off += (size_t)BB*ENC*4;           // 256 KB
    float* Hbuf    = (float*)(ws + off); off += (size_t)(TSTEPS+1)*BB*HD*4; // 1.38 MB
    bf16*  lstm_in = (bf16*) (ws + off); off += (size_t)BB*KCAT*2;          // 192 KB
    bf16*  Hall_bf = (bf16*) (ws + off); off += (size_t)TSTEPS*BB*HD*2;     // 640 KB
    bf16*  wcat    = (bf16*) (ws + off); off += (size_t)4*HD*KCAT*2;        // 12.6 MB
    bf16*  fcnw_bf = (bf16*) (ws + off); off += (size_t)VCB*HD*2;           // 31.25 MB
    bf16*  Ww_bf   = (bf16*) (ws + off); off += (size_t)ATTD*HD*2;          // 512 KB
    bf16*  feat_bf = (bf16*) (ws + off); off += (size_t)BB*NF*ENC*2;        // 6.4 MB
    int*   flag    = (int*)  (ws + off); off += 256;
    unsigned* bar  = (unsigned*)(ws + off); off += 2048;
    if (ws_size < off) return;

    k_detect    <<<1, 256, 0, stream>>>(emb, flag, bar);
    k_prep_gates<<<2048, 256, 0, stream>>>(w_ih, w_hh, wcat, flag);
    k_prep_cvt8 <<<2048, 256, 0, stream>>>(fcn_w, fcnw_bf, (size_t)VCB*HD/8, flag);
    k_prep_cvt8 <<<128, 256, 0, stream>>>(W_w, Ww_bf, (size_t)ATTD*HD/8, flag);
    k_prep_cvt8 <<<1024, 256, 0, stream>>>(feat, feat_bf, (size_t)BB*NF*ENC/8, flag);
    k_mean      <<<BB, 256, 0, stream>>>(feat, mean_f, flag);
    k_init_hc   <<<64, 256, 0, stream>>>(mean_f, ihw, ihb, icw, icb, Hbuf, c_f32, flag);
    k_uhs       <<<dim3(98, 8), 256, 0, stream>>>(feat_bf, U_w, U_b, u_hs, flag);

    // whole 20-step decode loop in one cooperative launch (2 relaxed barriers/step)
    {
        void* kargs[18] = {
            (void*)&Hbuf, (void*)&c_f32, (void*)&Ww_bf, (void*)&W_b,
            (void*)&u_hs, (void*)&A_w, (void*)&A_b, (void*)&caps,
            (void*)&emb, (void*)&feat_bf, (void*)&lstm_in, (void*)&wcat,
            (void*)&b_ih, (void*)&b_hh, (void*)&Hall_bf, (void*)&d_out,
            (void*)&flag, (void*)&bar
        };
        hipLaunchCooperativeKernel((void*)k_decode, dim3(NBLK), dim3(DTPB),
                                   kargs, 0, stream);
    }

    k_fcn<<<477, 256, 0, stream>>>(Hall_bf, fcnw_bf, fcn_b, d_out, flag);
}

// Round 6
// 1546.542 us; speedup vs baseline: 1.0663x; 1.0022x over previous
//
#include <hip/hip_runtime.h>
#include <hip/hip_bf16.h>

// Problem constants (bert-base captioning decoder)
#define VCB 30522   // vocab
#define EMB 512     // embed size
#define ATTD 512    // attention dim
#define ENC 2048    // encoder dim
#define HD 512      // hidden dim
#define BB 32       // batch
#define NF 49       // image features
#define TSTEPS 20   // decode steps
#define EIN 2560    // EMB + ENC (lstm input)
#define KCAT 3072   // EIN + HD (fused gate GEMM K)
#define WSTRIDE 3080 // padded LDS row stride (bf16) -> row-to-row bank shift of 4
#define DTPB 512    // k_decode threads per block (8 waves)
#define NBLK 128    // k_decode blocks: each owns 4 hidden cols (16 wcat rows)
#define NGRP 8      // barrier groups (16 blocks each)

typedef __attribute__((ext_vector_type(8))) __bf16 bf16x8;
typedef __attribute__((ext_vector_type(4))) __bf16 bf16x4;
typedef __attribute__((ext_vector_type(4))) float floatx4;
typedef __hip_bfloat16 bf16;

__device__ __forceinline__ float bf2f(bf16 x){ return __bfloat162float(x); }
__device__ __forceinline__ bf16 f2bf(float x){ return __float2bfloat16(x); }
__device__ __forceinline__ float sigm(float x){ return 1.0f/(1.0f+expf(-x)); }
// fast tanh: (e^{2x}-1)/(e^{2x}+1) via hardware exp + rcp. |err| ~1e-6.
__device__ __forceinline__ float fast_tanh(float x){
    float e2 = __expf(2.0f*x);
    return 1.0f - 2.0f*__builtin_amdgcn_rcpf(e2 + 1.0f);
}

// ---- coherent (Infinity-Cache point) relaxed dword access -----------------
// Relaxed agent-scope atomics: sc1 accesses at the coherent point, no fences.
__device__ __forceinline__ unsigned coh_ld(const unsigned* p){
    return __hip_atomic_load(p, __ATOMIC_RELAXED, __HIP_MEMORY_SCOPE_AGENT);
}
__device__ __forceinline__ void coh_st(unsigned* p, unsigned v){
    __hip_atomic_store(p, v, __ATOMIC_RELAXED, __HIP_MEMORY_SCOPE_AGENT);
}
__device__ __forceinline__ unsigned pack2bf(float a, float b){
    unsigned short ua = __builtin_bit_cast(unsigned short, f2bf(a));
    unsigned short ub = __builtin_bit_cast(unsigned short, f2bf(b));
    return (unsigned)ua | ((unsigned)ub << 16);
}

// ---- dtype-adaptive load/store helpers (f=1: data is f32; f=0: bf16) ------
__device__ __forceinline__ float ld1(const void* base, size_t idx, int f){
    if (f) return ((const float*)base)[idx];
    return bf2f(((const bf16*)base)[idx]);
}
__device__ __forceinline__ bf16x8 ldbf8(const void* base, size_t idx, int f){
    if (f){
        const float* p = (const float*)base + idx;
        float4 a = *(const float4*)p, b = *(const float4*)(p+4);
        bf16x8 r;
        r[0]=(__bf16)a.x; r[1]=(__bf16)a.y; r[2]=(__bf16)a.z; r[3]=(__bf16)a.w;
        r[4]=(__bf16)b.x; r[5]=(__bf16)b.y; r[6]=(__bf16)b.z; r[7]=(__bf16)b.w;
        return r;
    }
    return *(const bf16x8*)((const bf16*)base + idx);
}
__device__ __forceinline__ bf16x8 bf8_of_f32(const float* p){
    float4 a = *(const float4*)p, b = *(const float4*)(p+4);
    bf16x8 r;
    r[0]=(__bf16)a.x; r[1]=(__bf16)a.y; r[2]=(__bf16)a.z; r[3]=(__bf16)a.w;
    r[4]=(__bf16)b.x; r[5]=(__bf16)b.y; r[6]=(__bf16)b.z; r[7]=(__bf16)b.w;
    return r;
}
__device__ __forceinline__ void st1(void* base, size_t idx, float v, int f){
    if (f) ((float*)base)[idx] = v;
    else   ((bf16*)base)[idx] = f2bf(v);
}

#define MFMA16(a,b,c) __builtin_amdgcn_mfma_f32_16x16x32_bf16(a,b,c,0,0,0)
// Verified fragment layout (learn_hip m89/m91):
//   A: lane holds A[m=lane&15][k=(lane>>4)*8+j]   (row-major [M][K])
//   B: lane holds Bt[n=lane&15][k=(lane>>4)*8+j]  (row-major [N][K])
//   D: lane holds D[row=(lane>>4)*4+r][col=lane&15]

// ---- grid barrier v3: counters isolated from polling ----------------------
// bar[g*16]      : per-group arrival counters (8 groups x 16 blocks, 64B apart)
// bar[256]       : root counter (8 adds per epoch)
// bar[512+g*16]  : per-group RELEASE lines — the ONLY lines polled (<=16
//                  pollers each), so the arrival/root RMW chain never queues
//                  behind poll traffic (r5 post-mortem: ~128 pollers on the
//                  root line ~= 20us/barrier).
// Monotonic epochs; all relaxed agent-scope; __syncthreads drains vmcnt(0)
// before arrival (orders prior sc1 data stores).
__device__ __forceinline__ void gbar(unsigned* bar, unsigned ep){
    __syncthreads();
    if (threadIdx.x == 0){
        unsigned g = blockIdx.x >> 4;
        unsigned* grp  = bar + (g << 4);
        unsigned* root = bar + 256;
        unsigned* rel  = bar + 512 + (g << 4);
        unsigned old = __hip_atomic_fetch_add(grp, 1u, __ATOMIC_RELAXED, __HIP_MEMORY_SCOPE_AGENT);
        if (old + 1u == ep*16u){
            unsigned rold = __hip_atomic_fetch_add(root, 1u, __ATOMIC_RELAXED, __HIP_MEMORY_SCOPE_AGENT);
            if (rold + 1u == ep*NGRP){
#pragma unroll
                for (int i = 0; i < NGRP; ++i)
                    coh_st(bar + 512 + (i << 4), ep);
            }
        }
        int spins = 0;
        while (coh_ld(rel) < ep){
            if (++spins > 2) __builtin_amdgcn_s_sleep(8);
        }
    }
    __syncthreads();
}

// ---------------- kernel 0: dtype detect + barrier zero --------------------
__global__ void k_detect(const void* emb, int* flag, unsigned* bar){
    int tid = threadIdx.x;
    __shared__ int bad;
    if (tid == 0) bad = 0;
    for (int i = tid; i < 1024; i += 256) bar[i] = 0u;
    __syncthreads();
    const unsigned short* u = (const unsigned short*)emb;
    int local = 0;
    for (int i = tid; i < 4096; i += 256){
        int e = (u[i] >> 7) & 0xFF;
        if (e > 140) local = 1;           // |v| > 2^13: impossible for real data
    }
    if (local) bad = 1;
    __syncthreads();
    if (tid == 0) *flag = bad;
}

// ---------------- prep kernels: convert weights to bf16 once ---------------
// wcat[r][0..2559] = w_ih[r], wcat[r][2560..3071] = w_hh[r]   (r = gate*512+n)
__global__ void k_prep_gates(const void* w_ih, const void* w_hh, bf16* __restrict__ wcat,
                             const int* __restrict__ flag){
    int ff = *flag;
    int r = blockIdx.x, tid = threadIdx.x;
    for (int i = tid*8; i < KCAT; i += 2048){
        bf16x8 v;
        if (i + 8 <= EIN){
            v = ldbf8(w_ih, (size_t)r*EIN + i, ff);
        } else if (i >= EIN){
            v = ldbf8(w_hh, (size_t)r*HD + (i - EIN), ff);
        } else {
#pragma unroll
            for (int j = 0; j < 8; ++j){
                int k = i + j;
                v[j] = (__bf16)((k < EIN) ? ld1(w_ih, (size_t)r*EIN + k, ff)
                                          : ld1(w_hh, (size_t)r*HD + (k - EIN), ff));
            }
        }
        *(bf16x8*)(wcat + (size_t)r*KCAT + i) = v;
    }
}
// vectorized convert, n must be divisible by 8
__global__ void k_prep_cvt8(const void* src, bf16* __restrict__ dst, size_t n8,
                            const int* __restrict__ flag){
    int ff = *flag;
    size_t idx = (size_t)blockIdx.x*256 + threadIdx.x;
    size_t stride = (size_t)gridDim.x*256;
    for (size_t i = idx; i < n8; i += stride)
        *(bf16x8*)(dst + i*8) = ldbf8(src, i*8, ff);
}

// ---------------- kernel 1: mean over feature positions (f32 out) ----------
__global__ void k_mean(const void* feat, float* __restrict__ mean_f,
                       const int* __restrict__ flag){
    int ff = *flag;
    int b = blockIdx.x, tid = threadIdx.x;
    for (int i = 0; i < ENC/256; ++i){
        int e = i*256 + tid;
        size_t base = (size_t)b*NF*ENC + e;
        float s = 0.f;
        for (int n = 0; n < NF; ++n) s += ld1(feat, base + (size_t)n*ENC, ff);
        mean_f[b*ENC + e] = s * (1.0f/49.0f);
    }
}

// ---------------- kernel 2: h0/c0 = mean_f @ [ihw|icw]^T + b (MFMA) --------
__global__ void k_init_hc(const float* __restrict__ mean_f,
                          const void* ihw, const void* ihb,
                          const void* icw, const void* icb,
                          float* __restrict__ Hbuf, float* __restrict__ c_f32,
                          const int* __restrict__ flag){
    int ff = *flag;
    int tid = threadIdx.x, wave = tid>>6, lane = tid&63, quad = lane>>4, lq = lane&15;
    int n0 = blockIdx.x*16;
    int ng = n0 + lq;
    const void* w = (ng < HD) ? ihw : icw;
    size_t wrow = (size_t)(ng < HD ? ng : ng - HD)*ENC;
    floatx4 acc[2] = {{0,0,0,0},{0,0,0,0}};
    int kb = wave*512;
    for (int kk = 0; kk < 16; ++kk){
        int k = kb + kk*32 + quad*8;
        bf16x8 bfr = ldbf8(w, wrow + k, ff);
#pragma unroll
        for (int mt = 0; mt < 2; ++mt){
            bf16x8 afr = bf8_of_f32(mean_f + (size_t)(mt*16+lq)*ENC + k);
            acc[mt] = MFMA16(afr, bfr, acc[mt]);
        }
    }
    __shared__ float red[4][2][16][16];
#pragma unroll
    for (int mt = 0; mt < 2; ++mt)
        for (int r = 0; r < 4; ++r)
            red[wave][mt][quad*4+r][lq] = acc[mt][r];
    __syncthreads();
    for (int rep = 0; rep < 2; ++rep){
        int idx = rep*256 + tid;
        int mt = idx>>8, mm = (idx>>4)&15, nn = idx&15;
        float v = red[0][mt][mm][nn]+red[1][mt][mm][nn]+red[2][mt][mm][nn]+red[3][mt][mm][nn];
        int n_g = n0 + nn, b = mt*16 + mm;
        if (n_g < HD) Hbuf[b*HD + n_g]        = v + ld1(ihb, n_g, ff);
        else          c_f32[b*HD + (n_g-HD)]  = v + ld1(icb, n_g - HD, ff);
    }
}

// ---------------- kernel 3: u_hs = feat_bf @ U_w^T + U_b (MFMA, f32 out) ---
__global__ void k_uhs(const bf16* __restrict__ feat_bf, const void* U_w, const void* U_b,
                      float* __restrict__ u_hs, const int* __restrict__ flag){
    int ff = *flag;
    int tid = threadIdx.x, wave = tid>>6, lane = tid&63, quad = lane>>4, lq = lane&15;
    int m0 = blockIdx.x*16;
    int n0 = blockIdx.y*64 + wave*16;
    size_t arow = (size_t)(m0+lq)*ENC;
    size_t brow = (size_t)(n0+lq)*ENC;
    floatx4 acc = {0,0,0,0};
    for (int kk = 0; kk < ENC/32; ++kk){
        int k = kk*32 + quad*8;
        bf16x8 afr = *(const bf16x8*)(feat_bf + arow + k);
        bf16x8 bfr = ldbf8(U_w,  brow + k, ff);
        acc = MFMA16(afr, bfr, acc);
    }
    float ub = ld1(U_b, n0+lq, ff);
    for (int r = 0; r < 4; ++r){
        int m = m0 + quad*4 + r;
        u_hs[(size_t)m*ATTD + n0 + lq] = acc[r] + ub;
    }
}

// ---------------- kernel 4: persistent cooperative decode loop -------------
// Grid 128 x 512 threads. Block bid owns hidden cols {4bid..4bid+3}: its 16
// wcat rows (98.5 KB) live in LDS for the whole loop; its c state in LDS.
// Cross-block data (lstm_in, Hbuf) via relaxed agent-scope (sc1) dwords.
// Per step: phase A (blocks 0..31 = batch) attention -> lstm_in[emb|ctx];
// gbar; phase B (waves 0-3) gates MFMA + LSTM pointwise -> h,c; gbar.
__global__ void __launch_bounds__(DTPB) k_decode(
        float* __restrict__ Hbuf, const float* __restrict__ c0_f32,
        const bf16* __restrict__ Ww_bf, const void* __restrict__ W_b,
        const float* __restrict__ u_hs, const void* __restrict__ A_w,
        const void* __restrict__ A_b, const int* __restrict__ captions,
        const void* __restrict__ emb, const bf16* __restrict__ feat_bf,
        bf16* __restrict__ lstm_in, const bf16* __restrict__ wcat,
        const void* __restrict__ b_ih, const void* __restrict__ b_hh,
        bf16* __restrict__ Hall_bf, void* __restrict__ d_out,
        const int* __restrict__ flag, unsigned* __restrict__ bar)
{
    const int ff = *flag;
    const int bid = blockIdx.x, tid = threadIdx.x;
    const int wave = tid>>6, lane = tid&63, quad = lane>>4, lq = lane&15;

    __shared__ bf16  wlds[16*WSTRIDE];  // 98.56 KB: this block's 16 wcat rows
    __shared__ float ubuf[2048];        // 8 KB: attention scratch UNION mfma red
    __shared__ float aw_s[ATTD];        // 2 KB (attention blocks only)
    __shared__ float c_loc[BB*4];       // persistent c state (32 b x 4 cols)
    __shared__ float gbias[16];         // b_ih+b_hh for this block's 16 rows

    unsigned* lin_u = (unsigned*)lstm_in;     // lstm_in as dwords (bf16 pairs)

    // ---- prologue: load persistent state ----
    for (int n = 0; n < 16; ++n){
        int g = n>>2, j = n&3;
        const bf16* src = wcat + (size_t)(g*HD + (bid<<2) + j)*KCAT;
        for (int c8 = tid; c8 < KCAT/8; c8 += DTPB)
            *(bf16x8*)(wlds + n*WSTRIDE + c8*8) = *(const bf16x8*)(src + c8*8);
    }
    if (tid < 128){
        int bb = tid&31, j = tid>>5, col = (bid<<2)+j;
        c_loc[bb*4+j] = c0_f32[bb*HD + col];   // plain: pre-kernel data
    }
    if (tid < 64){
        // h-section of lstm_in for t=0 (h0 from Hbuf slot 0), dword-packed
        int bb = tid&31, j2 = tid>>5;
        int c0 = (bid<<2) + 2*j2;
        float h0 = Hbuf[bb*HD + c0], h1 = Hbuf[bb*HD + c0 + 1];
        coh_st(lin_u + (size_t)bb*(KCAT/2) + (EIN + c0)/2, pack2bf(h0, h1));
    }
    if (tid < 16){
        int g = tid>>2, j = tid&3, col = (bid<<2)+j;
        gbias[tid] = ld1(b_ih, g*HD+col, ff) + ld1(b_hh, g*HD+col, ff);
    }
    if (bid < BB)
        for (int i = tid; i < ATTD; i += DTPB) aw_s[i] = ld1(A_w, i, ff);
    __syncthreads();

    // union views of ubuf (phase A scratch vs phase B reduce — never live
    // at the same time; gbar + __syncthreads order every transition)
    float* h_sh    = ubuf;          // [512]
    float* wah_s   = ubuf + 512;    // [512]
    float* sc_s    = ubuf + 1024;   // [52]
    float* alpha_s = ubuf + 1088;   // [52]
    float (*red)[2][16][16] = (float (*)[2][16][16])ubuf;  // [4][2][16][16]

    unsigned ep = 0;

    for (int t = 0; t < TSTEPS; ++t){
        // ===== phase A: attention (one block per batch b) =====
        if (bid < BB){
            const int b = bid;
            const unsigned* hrow = (const unsigned*)(Hbuf + (size_t)t*BB*HD + b*HD);
            for (int i = tid; i < HD; i += DTPB)
                h_sh[i] = __uint_as_float(coh_ld(hrow + i));
            int cap = captions[b*21 + t];
            for (int e2 = tid; e2 < EMB/2; e2 += DTPB){
                float a = ld1(emb, (size_t)cap*EMB + 2*e2,     ff);
                float c = ld1(emb, (size_t)cap*EMB + 2*e2 + 1, ff);
                coh_st(lin_u + (size_t)b*(KCAT/2) + e2, pack2bf(a, c));
            }
            __syncthreads();
            // w_ah[a] = h . W_w[a] + W_b[a]  (1 row/thread, 4 split accs)
            for (int a = tid; a < ATTD; a += DTPB){
                const bf16* wr = Ww_bf + (size_t)a*HD;
                float s0=0.f, s1=0.f, s2=0.f, s3=0.f;
                for (int k = 0; k < HD; k += 8){
                    bf16x8 wv = *(const bf16x8*)(wr + k);
                    s0 += (float)wv[0]*h_sh[k+0] + (float)wv[4]*h_sh[k+4];
                    s1 += (float)wv[1]*h_sh[k+1] + (float)wv[5]*h_sh[k+5];
                    s2 += (float)wv[2]*h_sh[k+2] + (float)wv[6]*h_sh[k+6];
                    s3 += (float)wv[3]*h_sh[k+3] + (float)wv[7]*h_sh[k+7];
                }
                wah_s[a] = ((s0+s1)+(s2+s3)) + ld1(W_b, a, ff);
            }
            __syncthreads();
            // scores[n] = A_w . tanh(u_hs[b,n,:] + w_ah) + A_b  (8 waves)
            {
                int a0 = lane*8;
                for (int n = wave; n < NF; n += 8){
                    const float* up = u_hs + (size_t)(b*NF + n)*ATTD + a0;
                    float4 u0 = *(const float4*)up;
                    float4 u1 = *(const float4*)(up + 4);
                    float p0 = fast_tanh(u0.x + wah_s[a0+0])*aw_s[a0+0]
                             + fast_tanh(u0.y + wah_s[a0+1])*aw_s[a0+1]
                             + fast_tanh(u0.z + wah_s[a0+2])*aw_s[a0+2]
                             + fast_tanh(u0.w + wah_s[a0+3])*aw_s[a0+3];
                    float p1 = fast_tanh(u1.x + wah_s[a0+4])*aw_s[a0+4]
                             + fast_tanh(u1.y + wah_s[a0+5])*aw_s[a0+5]
                             + fast_tanh(u1.z + wah_s[a0+6])*aw_s[a0+6]
                             + fast_tanh(u1.w + wah_s[a0+7])*aw_s[a0+7];
                    float p = p0 + p1;
                    for (int off = 32; off; off >>= 1) p += __shfl_down(p, off);
                    if (lane == 0) sc_s[n] = p + ld1(A_b, 0, ff);
                }
            }
            __syncthreads();
            // softmax over 49 (wave 0) + alpha output
            if (wave == 0){
                float v = (lane < NF) ? sc_s[lane] : -1e30f;
                float mx = v;
                for (int off = 32; off; off >>= 1) mx = fmaxf(mx, __shfl_down(mx, off));
                mx = __shfl(mx, 0);
                float e = (lane < NF) ? expf(v - mx) : 0.f;
                float s = e;
                for (int off = 32; off; off >>= 1) s += __shfl_down(s, off);
                s = __shfl(s, 0);
                if (lane < NF){
                    float al = e / s;
                    alpha_s[lane] = al;
                    st1(d_out, (size_t)BB*TSTEPS*VCB + (size_t)b*(TSTEPS*NF) + t*NF + lane, al, ff);
                }
            }
            __syncthreads();
            // context[e] = sum_n alpha[n]*feat_bf[b,n,e]; thread owns 4 contig e
            {
                int e0 = tid*4;
                float acc[4] = {0,0,0,0};
#pragma unroll 7
                for (int n = 0; n < NF; ++n){
                    float al = alpha_s[n];
                    bf16x4 v = *(const bf16x4*)(feat_bf + (size_t)b*NF*ENC + (size_t)n*ENC + e0);
#pragma unroll
                    for (int j = 0; j < 4; ++j) acc[j] += al*(float)v[j];
                }
                unsigned* lrow = lin_u + (size_t)b*(KCAT/2) + (EMB + e0)/2;
                coh_st(lrow,     pack2bf(acc[0], acc[1]));
                coh_st(lrow + 1, pack2bf(acc[2], acc[3]));
            }
        }
        gbar(bar, ++ep);

        // ===== phase B: gates MFMA (LDS wcat, waves 0-3) + LSTM pointwise ===
        if (wave < 4){
            int kb = wave*768;                      // K split 4x768 over waves
            floatx4 acc0 = {0,0,0,0}, acc1 = {0,0,0,0};
            const bf16* wrow = wlds + (size_t)lq*WSTRIDE;  // 16 distinct B-rows
            const unsigned* ar0 = lin_u + (size_t)lq*(KCAT/2);
            const unsigned* ar1 = lin_u + (size_t)(16+lq)*(KCAT/2);
            union U8 { unsigned u[4]; bf16x8 v; };
#pragma unroll
            for (int kk = 0; kk < 24; ++kk){
                int kd = (kb + kk*32 + quad*8) >> 1;   // dword index
                bf16x8 bfr = *(const bf16x8*)(wrow + kb + kk*32 + quad*8);
                U8 a0, a1;
#pragma unroll
                for (int q = 0; q < 4; ++q){
                    a0.u[q] = coh_ld(ar0 + kd + q);
                    a1.u[q] = coh_ld(ar1 + kd + q);
                }
                acc0 = MFMA16(a0.v, bfr, acc0);
                acc1 = MFMA16(a1.v, bfr, acc1);
            }
#pragma unroll
            for (int r = 0; r < 4; ++r){
                red[wave][0][quad*4+r][lq] = acc0[r];
                red[wave][1][quad*4+r][lq] = acc1[r];
            }
        }
        __syncthreads();
        if (tid < 64){
            int bb = tid&31, j2 = tid>>5;           // j2: col pair 0/1
            int mt = bb>>4, mm = bb&15;
            float hn[2];
#pragma unroll
            for (int sub = 0; sub < 2; ++sub){
                int j = 2*j2 + sub;                 // col-in-block 0..3
                float G[4];
#pragma unroll
                for (int g = 0; g < 4; ++g){
                    int n = g*4 + j;                // B-row n = gate*4 + col
                    G[g] = red[0][mt][mm][n] + red[1][mt][mm][n]
                         + red[2][mt][mm][n] + red[3][mt][mm][n] + gbias[n];
                }
                float c_old = c_loc[bb*4+j];
                float c_new = sigm(G[1])*c_old + sigm(G[0])*tanhf(G[2]);
                float h_new = sigm(G[3])*tanhf(c_new);
                c_loc[bb*4+j] = c_new;
                hn[sub] = h_new;
            }
            int colb = (bid<<2) + 2*j2;
            unsigned* hb = (unsigned*)(Hbuf + (size_t)(t+1)*BB*HD + bb*HD + colb);
            coh_st(hb,     __float_as_uint(hn[0]));
            coh_st(hb + 1, __float_as_uint(hn[1]));
            ((unsigned*)Hall_bf)[((size_t)t*BB*HD + bb*HD + colb) >> 1] = pack2bf(hn[0], hn[1]);
            coh_st(lin_u + (size_t)bb*(KCAT/2) + (EIN + colb)/2, pack2bf(hn[0], hn[1]));
        }
        gbar(bar, ++ep);
    }
}

// ---------------- kernel 6: preds = Hall_bf @ fcnw_bf^T + fcn_b ------------
__global__ void __launch_bounds__(256) k_fcn(const bf16* __restrict__ Hall_bf,
                                             const bf16* __restrict__ fcnw_bf,
                                             const void* fcn_b, void* d_out,
                                             const int* __restrict__ flag){
    int ff = *flag;
    int tid = threadIdx.x, wave = tid>>6, lane = tid&63, quad = lane>>4, lq = lane&15;
    int n0 = blockIdx.x*64 + wave*16;
    int v = n0 + lq;
    int vc = (v < VCB) ? v : (VCB-1);
    const bf16* brow = fcnw_bf + (size_t)vc*HD;
    bf16x8 bfr[16];
#pragma unroll
    for (int kk = 0; kk < 16; ++kk) bfr[kk] = *(const bf16x8*)(brow + kk*32 + quad*8);
    float bias = ld1(fcn_b, vc, ff);
    for (int mt = 0; mt < 40; ++mt){
        const bf16* arow = Hall_bf + (size_t)(mt*16 + lq)*HD;
        floatx4 acc = {0,0,0,0};
#pragma unroll
        for (int kk = 0; kk < 16; ++kk){
            bf16x8 afr = *(const bf16x8*)(arow + kk*32 + quad*8);
            acc = MFMA16(afr, bfr[kk], acc);
        }
        if (v < VCB){
#pragma unroll
            for (int r = 0; r < 4; ++r){
                int m = mt*16 + quad*4 + r;
                int b = m & 31, tt = m >> 5;
                st1(d_out, (size_t)b*(TSTEPS*VCB) + (size_t)tt*VCB + v, acc[r] + bias, ff);
            }
        }
    }
}

// ---------------- host launch ---------------------------------------------
extern "C" void kernel_launch(void* const* d_in, const int* in_sizes, int n_in,
                              void* d_out, int out_size, void* d_ws, size_t ws_size,
                              hipStream_t stream) {
    const void* feat  = d_in[0];
    const int*  caps  = (const int*)d_in[1];
    const void* emb   = d_in[2];
    const void* W_w   = d_in[3];
    const void* W_b   = d_in[4];
    const void* U_w   = d_in[5];
    const void* U_b   = d_in[6];
    const void* A_w   = d_in[7];
    const void* A_b   = d_in[8];
    const void* ihw   = d_in[9];
    const void* ihb   = d_in[10];
    const void* icw   = d_in[11];
    const void* icb   = d_in[12];
    const void* w_ih  = d_in[13];
    const void* w_hh  = d_in[14];
    const void* b_ih  = d_in[15];
    const void* b_hh  = d_in[16];
    const void* fcn_w = d_in[17];
    const void* fcn_b = d_in[18];

    // workspace layout (16B-aligned)
    char* ws = (char*)d_ws;
    size_t off = 0;
    float* u_hs    = (float*)(ws + off); off += (size_t)BB*NF*ATTD*4;       // 3.2 MB
    float* c_f32   = (float*)(ws + off); off += (size_t)BB*HD*4;            // 64 KB
    float* mean_f  = (float*)(ws + off); off += (size_t)BB*ENC*4;           // 256 KB
    float* Hbuf    = (float*)(ws + off); off += (size_t)(TSTEPS+1)*BB*HD*4; // 1.38 MB
    bf16*  lstm_in = (bf16*) (ws + off); off += (size_t)BB*KCAT*2;          // 192 KB
    bf16*  Hall_bf = (bf16*) (ws + off); off += (size_t)TSTEPS*BB*HD*2;     // 640 KB
    bf16*  wcat    = (bf16*) (ws + off); off += (size_t)4*HD*KCAT*2;        // 12.6 MB
    bf16*  fcnw_bf = (bf16*) (ws + off); off += (size_t)VCB*HD*2;           // 31.25 MB
    bf16*  Ww_bf   = (bf16*) (ws + off); off += (size_t)ATTD*HD*2;          // 512 KB
    bf16*  feat_bf = (bf16*) (ws + off); off += (size_t)BB*NF*ENC*2;        // 6.4 MB
    int*   flag    = (int*)  (ws + off); off += 256;
    unsigned* bar  = (unsigned*)(ws + off); off += 4096;
    if (ws_size < off) return;

    k_detect    <<<1, 256, 0, stream>>>(emb, flag, bar);
    k_prep_gates<<<2048, 256, 0, stream>>>(w_ih, w_hh, wcat, flag);
    k_prep_cvt8 <<<2048, 256, 0, stream>>>(fcn_w, fcnw_bf, (size_t)VCB*HD/8, flag);
    k_prep_cvt8 <<<128, 256, 0, stream>>>(W_w, Ww_bf, (size_t)ATTD*HD/8, flag);
    k_prep_cvt8 <<<1024, 256, 0, stream>>>(feat, feat_bf, (size_t)BB*NF*ENC/8, flag);
    k_mean      <<<BB, 256, 0, stream>>>(feat, mean_f, flag);
    k_init_hc   <<<64, 256, 0, stream>>>(mean_f, ihw, ihb, icw, icb, Hbuf, c_f32, flag);
    k_uhs       <<<dim3(98, 8), 256, 0, stream>>>(feat_bf, U_w, U_b, u_hs, flag);

    // whole 20-step decode loop in one cooperative launch (2 barriers/step)
    {
        void* kargs[18] = {
            (void*)&Hbuf, (void*)&c_f32, (void*)&Ww_bf, (void*)&W_b,
            (void*)&u_hs, (void*)&A_w, (void*)&A_b, (void*)&caps,
            (void*)&emb, (void*)&feat_bf, (void*)&lstm_in, (void*)&wcat,
            (void*)&b_ih, (void*)&b_hh, (void*)&Hall_bf, (void*)&d_out,
            (void*)&flag, (void*)&bar
        };
        hipLaunchCooperativeKernel((void*)k_decode, dim3(NBLK), dim3(DTPB),
                                   kargs, 0, stream);
    }

    k_fcn<<<477, 256, 0, stream>>>(Hall_bf, fcnw_bf, fcn_b, d_out, flag);
}